// Round 11
// baseline (741.026 us; speedup 1.0000x reference)
//
#include <hip/hip_runtime.h>

#define N_NODES 100000
#define N_EDGES 3200000
#define IN_DIM 256
#define HIDDEN 128
#define OUT_DIM 64

#define CHUNK 3072       // edges per scatter block
#define NPT (CHUNK / 256)
#define NPB ((N_EDGES + CHUNK - 1) / CHUNK)   // 1042 scatter blocks
#define SCB 2048         // rows per scan block
#define NSC ((N_NODES + SCB - 1) / SCB)       // 49 scan blocks

typedef unsigned int uint32;
typedef unsigned short ushort16;

typedef short short8 __attribute__((ext_vector_type(8)));   // 8 bf16 (4 VGPRs)
typedef float f32x4 __attribute__((ext_vector_type(4)));    // MFMA acc

// round-to-nearest-even f32 -> bf16
__device__ __forceinline__ ushort16 f2bf(float f) {
    uint32 u = __float_as_uint(f);
    u += 0x7fffu + ((u >> 16) & 1u);
    return (ushort16)(u >> 16);
}

// split f32 into bf16 hi + bf16 lo, f ~= hi + lo (error ~2^-16 rel)
__device__ __forceinline__ void splitbf(float f, unsigned short& hi, unsigned short& lo) {
    uint32 u = __float_as_uint(f);
    uint32 r = u + 0x7fffu + ((u >> 16) & 1u);
    hi = (unsigned short)(r >> 16);
    float hf = __uint_as_float((r >> 16) << 16);
    float res = f - hf;                    // exact (Sterbenz: same binade)
    uint32 v = __float_as_uint(res);
    lo = (unsigned short)((v + 0x7fffu + ((v >> 16) & 1u)) >> 16);
}

// ---------------- row histogram: global atomics over 100K counters (low contention) ----

__global__ __launch_bounds__(256)
void hist_row(const int* __restrict__ edst, int* __restrict__ rcnt, int E) {
    int i = blockIdx.x * 256 + threadIdx.x;
    int stride = gridDim.x * 256;
    for (; i < E; i += stride)
        atomicAdd(&rcnt[edst[i]], 1);
}

// ---------------- 3-stage exclusive scan over 100K row counts ----------------

__global__ __launch_bounds__(256)
void scan_rows_a(const int* __restrict__ rcnt, int* __restrict__ bsum) {
    __shared__ int st[256];
    int tid = threadIdx.x;
    int base = blockIdx.x * SCB + tid * 8;
    int s = 0;
#pragma unroll
    for (int k = 0; k < 8; k++) {
        int idx = base + k;
        if (idx < N_NODES) s += rcnt[idx];
    }
    st[tid] = s;
    __syncthreads();
    for (int off = 128; off > 0; off >>= 1) {
        if (tid < off) st[tid] += st[tid + off];
        __syncthreads();
    }
    if (tid == 0) bsum[blockIdx.x] = st[0];
}

__global__ __launch_bounds__(64)
void scan_rows_b(const int* __restrict__ bsum, int* __restrict__ boff,
                 int* __restrict__ row_ptr, int E) {
    int tid = threadIdx.x;
    int v = (tid < NSC) ? bsum[tid] : 0;
    int sum = v;
#pragma unroll
    for (int off = 1; off < 64; off <<= 1) {
        int up = __shfl_up(sum, off);
        if (tid >= off) sum += up;
    }
    if (tid < NSC) boff[tid] = sum - v;
    if (tid == 0) row_ptr[N_NODES] = E;
}

__global__ __launch_bounds__(256)
void scan_rows_c(const int* __restrict__ rcnt, const int* __restrict__ boff,
                 int* __restrict__ row_ptr, int* __restrict__ cursor) {
    __shared__ int st[256];
    int tid = threadIdx.x;
    int base = blockIdx.x * SCB + tid * 8;
    int v[8];
    int s = 0;
#pragma unroll
    for (int k = 0; k < 8; k++) {
        int idx = base + k;
        v[k] = (idx < N_NODES) ? rcnt[idx] : 0;
        s += v[k];
    }
    st[tid] = s;
    __syncthreads();
    for (int off = 1; off < 256; off <<= 1) {
        int t = (tid >= off) ? st[tid - off] : 0;
        __syncthreads();
        st[tid] += t;
        __syncthreads();
    }
    int run = boff[blockIdx.x] + st[tid] - s;
#pragma unroll
    for (int k = 0; k < 8; k++) {
        int idx = base + k;
        if (idx < N_NODES) { row_ptr[idx] = run; cursor[idx] = run; }
        run += v[k];
    }
}

// ---------------- weight split to MFMA-fragment-major layout (tiny, once) ----------------
// Layout: [kblk][nfrag][lane][8]  with  n = nfrag*16 + (lane&15), k = kblk*32 + (lane>>4)*8 + j

__global__ __launch_bounds__(256)
void splitw_kernel(const float* __restrict__ w1, const float* __restrict__ w2,
                   unsigned short* __restrict__ w1f_hi, unsigned short* __restrict__ w1f_lo,
                   unsigned short* __restrict__ w2f_hi, unsigned short* __restrict__ w2f_lo) {
    const int W1_SLOTS = (IN_DIM / 32) * (HIDDEN / 16) * 64;   // 4096
    const int W2_SLOTS = (HIDDEN / 32) * (OUT_DIM / 16) * 64;  // 1024
    int g = blockIdx.x * 256 + threadIdx.x;
    if (g < W1_SLOTS) {
        int lane = g & 63;
        int rest = g >> 6;
        int nfrag = rest & 7;              // HIDDEN/16 = 8
        int kblk = rest >> 3;
        int n = nfrag * 16 + (lane & 15);
        int k0 = kblk * 32 + (lane >> 4) * 8;
#pragma unroll
        for (int j = 0; j < 8; j++) {
            unsigned short h, l;
            splitbf(w1[(size_t)(k0 + j) * HIDDEN + n], h, l);
            w1f_hi[(size_t)g * 8 + j] = h;
            w1f_lo[(size_t)g * 8 + j] = l;
        }
    } else if (g < W1_SLOTS + W2_SLOTS) {
        int g2 = g - W1_SLOTS;
        int lane = g2 & 63;
        int rest = g2 >> 6;
        int nfrag = rest & 3;              // OUT_DIM/16 = 4
        int kblk = rest >> 2;
        int n = nfrag * 16 + (lane & 15);
        int k0 = kblk * 32 + (lane >> 4) * 8;
#pragma unroll
        for (int j = 0; j < 8; j++) {
            unsigned short h, l;
            splitbf(w2[(size_t)(k0 + j) * OUT_DIM + n], h, l);
            w2f_hi[(size_t)g2 * 8 + j] = h;
            w2f_lo[(size_t)g2 * 8 + j] = l;
        }
    }
}

// ---------------- MFMA GEMM body (device fn): C(bf16) = A(fp32) @ B, split-bf16 3-product ----

template <int K, int BN>
__device__ __forceinline__ void gemm_body(int bx, char* smem, const float* __restrict__ A,
                                          const unsigned short* __restrict__ Bf_hi,
                                          const unsigned short* __restrict__ Bf_lo,
                                          ushort16* __restrict__ C, int M) {
    constexpr int BM = 128, BK = 64;
    constexpr int NF = BN / 32;
    unsigned short* Ah = (unsigned short*)smem;                 // 16384 B
    unsigned short* Al = (unsigned short*)(smem + BM * BK * 2); // 16384 B

    int tid = threadIdx.x;
    int wid = tid >> 6, lane = tid & 63;
    int wr = wid >> 1, wc = wid & 1;
    int rowBase = bx * BM;
    int r = lane & 15, kg = lane >> 4;
    int swzmask = (lane & 7) << 4;

    f32x4 zero = {0.f, 0.f, 0.f, 0.f};
    f32x4 acc[4][NF];
#pragma unroll
    for (int m = 0; m < 4; m++)
#pragma unroll
        for (int n = 0; n < NF; n++) acc[m][n] = zero;

    int sk4 = (tid & 15) * 4;
    int sm0 = tid >> 4;

    for (int k0 = 0; k0 < K; k0 += BK) {
#pragma unroll
        for (int i = 0; i < 8; i++) {
            int m = sm0 + i * 16;
            int row = rowBase + m;
            float4 f = make_float4(0.f, 0.f, 0.f, 0.f);
            if (row < M) f = *(const float4*)(A + (size_t)row * K + k0 + sk4);
            ushort4 h, l;
            splitbf(f.x, h.x, l.x);
            splitbf(f.y, h.y, l.y);
            splitbf(f.z, h.z, l.z);
            splitbf(f.w, h.w, l.w);
            int bo = (m * BK + sk4) * 2;
            int swz = bo ^ ((m & 7) << 4);
            *(ushort4*)((char*)Ah + swz) = h;
            *(ushort4*)((char*)Al + swz) = l;
        }
        __syncthreads();

#pragma unroll
        for (int kk = 0; kk < BK / 32; kk++) {
            short8 ah[4], al[4];
            int abase = (wr * 64 + r) * (BK * 2) + kk * 64 + kg * 16;
#pragma unroll
            for (int m = 0; m < 4; m++) {
                int swz = (abase + m * (16 * BK * 2)) ^ swzmask;
                ah[m] = *(const short8*)((const char*)Ah + swz);
                al[m] = *(const short8*)((const char*)Al + swz);
            }
            short8 bh[NF], bl[NF];
            int kblk = (k0 >> 5) + kk;
#pragma unroll
            for (int n = 0; n < NF; n++) {
                int nf = wc * NF + n;
                size_t off = ((size_t)(kblk * (BN / 16) + nf) * 64 + lane) * 8;
                bh[n] = *(const short8*)(Bf_hi + off);
                bl[n] = *(const short8*)(Bf_lo + off);
            }
#pragma unroll
            for (int m = 0; m < 4; m++)
#pragma unroll
                for (int n = 0; n < NF; n++) {
                    acc[m][n] = __builtin_amdgcn_mfma_f32_16x16x32_bf16(ah[m], bh[n], acc[m][n], 0, 0, 0);
                    acc[m][n] = __builtin_amdgcn_mfma_f32_16x16x32_bf16(ah[m], bl[n], acc[m][n], 0, 0, 0);
                    acc[m][n] = __builtin_amdgcn_mfma_f32_16x16x32_bf16(al[m], bh[n], acc[m][n], 0, 0, 0);
                }
        }
        __syncthreads();
    }

#pragma unroll
    for (int m = 0; m < 4; m++) {
        int row0 = rowBase + wr * 64 + m * 16 + kg * 4;
#pragma unroll
        for (int j = 0; j < 4; j++) {
            int row = row0 + j;
            if (row < M) {
#pragma unroll
                for (int n = 0; n < NF; n++) {
                    int col = wc * (BN / 2) + n * 16 + r;
                    C[(size_t)row * BN + col] = f2bf(acc[m][n][j]);
                }
            }
        }
    }
}

// standalone GEMM kernel (layer 2)
template <int K, int BN>
__launch_bounds__(256)
__global__ void gemm_mfma(const float* __restrict__ A,
                          const unsigned short* __restrict__ Bf_hi,
                          const unsigned short* __restrict__ Bf_lo,
                          ushort16* __restrict__ C, int M) {
    __shared__ __align__(16) char smem[32768];
    gemm_body<K, BN>(blockIdx.x, smem, A, Bf_hi, Bf_lo, C, M);
}

// ---------------- fused: direct row scatter (blocks < NPB) + gemm1 (blocks >= NPB) ----------
// Each edge goes straight to its final row-sorted CSR slot: pos = cursor[dst]++ (global
// atomic over 100K counters -> low contention). Scattered 8B writes are the known cost
// (round-5 measurement); gemm1 blocks backfill the CUs and hide the latency.

__launch_bounds__(256)
__global__ void scatter_gemm1(const int* __restrict__ esrc, const int* __restrict__ edst,
                              const float* __restrict__ evals, int* __restrict__ cursor,
                              int2* __restrict__ part, int E,
                              const float* __restrict__ A,
                              const unsigned short* __restrict__ w1f_hi,
                              const unsigned short* __restrict__ w1f_lo,
                              ushort16* __restrict__ pre1, int M) {
    __shared__ __align__(16) char smem[32768];
    if (blockIdx.x >= NPB) {
        gemm_body<IN_DIM, HIDDEN>(blockIdx.x - NPB, smem, A, w1f_hi, w1f_lo, pre1, M);
        return;
    }
    int tid = threadIdx.x;
    long base = (long)blockIdx.x * CHUNK;
    int cnt = (int)min((long)CHUNK, (long)E - base);

    int d[NPT], sv[NPT]; float vv[NPT];
#pragma unroll
    for (int k = 0; k < NPT; k++) {
        int j = tid + k * 256;                 // coalesced loads
        d[k] = -1;
        if (j < cnt) {
            d[k]  = edst[base + j];
            sv[k] = esrc[base + j];
            vv[k] = evals[base + j];
        }
    }
#pragma unroll
    for (int k = 0; k < NPT; k++) {
        if (d[k] >= 0) {
            int pos = atomicAdd(&cursor[d[k]], 1);
            part[pos] = make_int2(sv[k], __float_as_int(vv[k]));
        }
    }
}

// ---------------- SpMM: wave per dst row, multi-edge-per-gather, 4-deep pipeline ----------
// Lane map: slot = lane % LPR covers the row's 16B chunks, sub = lane / LPR picks the edge.
// One global_load_dwordx4 fetches EPG edge-rows; 4 gathers in flight per wave.

template <int D, bool RELU>
__launch_bounds__(256)
__global__ void spmm_kernel(const ushort16* __restrict__ feat, const int2* __restrict__ csr_pair,
                            const int* __restrict__ row_ptr, float* __restrict__ out, int n) {
    constexpr int LPR = D * 2 / 16;      // lanes per row: 16 (D=128) or 8 (D=64)
    constexpr int EPG = 64 / LPR;        // edges per gather: 4 or 8
    constexpr int DEPTH = 4;
    int wid = threadIdx.x >> 6;
    int lane = threadIdx.x & 63;
    int row = blockIdx.x * 4 + wid;
    if (row >= n) return;
    int s = row_ptr[row], e = row_ptr[row + 1];

    int sub = lane / LPR;
    int slot = lane % LPR;
    const char* fbase = (const char*)feat + slot * 16;

    float acc[8];
#pragma unroll
    for (int j = 0; j < 8; j++) acc[j] = 0.f;

    for (int i = s; i < e; i += DEPTH * EPG) {
        int2 p[DEPTH]; float v[DEPTH]; uint4 u[DEPTH];
#pragma unroll
        for (int q = 0; q < DEPTH; q++) {
            int ii = i + q * EPG + sub;
            p[q] = csr_pair[min(ii, e - 1)];
            v[q] = (ii < e) ? __int_as_float(p[q].y) : 0.f;
        }
#pragma unroll
        for (int q = 0; q < DEPTH; q++)
            u[q] = *(const uint4*)(fbase + (size_t)p[q].x * (D * 2));
#pragma unroll
        for (int q = 0; q < DEPTH; q++) {
#pragma unroll
            for (int t = 0; t < 4; t++) {
                uint32 w = (&u[q].x)[t];
                acc[2 * t]     += v[q] * __uint_as_float(w << 16);
                acc[2 * t + 1] += v[q] * __uint_as_float(w & 0xffff0000u);
            }
        }
    }

    // fold the EPG edge-subgroups: lanes with equal slot sum across sub
#pragma unroll
    for (int m = LPR; m < 64; m <<= 1) {
#pragma unroll
        for (int j = 0; j < 8; j++) acc[j] += __shfl_xor(acc[j], m);
    }

    if (RELU) {
#pragma unroll
        for (int j = 0; j < 8; j++) acc[j] = acc[j] > 0.f ? acc[j] : 0.f;
    }

    if (lane < LPR) {
        float4* o = (float4*)(out + (size_t)row * D + slot * 8);
        o[0] = make_float4(acc[0], acc[1], acc[2], acc[3]);
        o[1] = make_float4(acc[4], acc[5], acc[6], acc[7]);
    }
}

// ---------------- launch ----------------

extern "C" void kernel_launch(void* const* d_in, const int* in_sizes, int n_in,
                              void* d_out, int out_size, void* d_ws, size_t ws_size,
                              hipStream_t stream) {
    const float* x    = (const float*)d_in[0];
    const float* adj  = (const float*)d_in[1];
    const float* w1   = (const float*)d_in[2];
    const float* w2   = (const float*)d_in[3];
    const int*   esrc = (const int*)d_in[4];
    const int*   edst = (const int*)d_in[5];
    float* out = (float*)d_out;

    const int N = N_NODES;
    const int E = N_EDGES;

    char* ws = (char*)d_ws;
    size_t off = 0;
    auto take = [&](size_t bytes) -> char* {
        char* p = ws + off;
        off = (off + bytes + 255) & ~(size_t)255;
        return p;
    };
    int*      rcnt    = (int*)take((size_t)N * 4);
    int*      bsum    = (int*)take((size_t)NSC * 4);
    int*      boff    = (int*)take((size_t)NSC * 4);
    int*      row_ptr = (int*)take((size_t)(N + 1) * 4);
    int*      cursor  = (int*)take((size_t)N * 4);
    int2*     part    = (int2*)take((size_t)E * 8);          // row-sorted CSR pairs
    ushort16* pre1    = (ushort16*)take((size_t)N * HIDDEN * 2);   // bf16
    ushort16* pre2    = (ushort16*)take((size_t)N * OUT_DIM * 2);  // bf16
    float*    h       = (float*)take((size_t)N * HIDDEN * 4);      // fp32
    unsigned short* w1f_hi = (unsigned short*)take((size_t)HIDDEN * IN_DIM * 2);
    unsigned short* w1f_lo = (unsigned short*)take((size_t)HIDDEN * IN_DIM * 2);
    unsigned short* w2f_hi = (unsigned short*)take((size_t)OUT_DIM * HIDDEN * 2);
    unsigned short* w2f_lo = (unsigned short*)take((size_t)OUT_DIM * HIDDEN * 2);

    // weight split to fragment-major (tiny)
    splitw_kernel<<<20, 256, 0, stream>>>(w1, w2, w1f_hi, w1f_lo, w2f_hi, w2f_lo);

    // CSR build: row histogram -> 3-stage scan -> direct scatter
    hipMemsetAsync(rcnt, 0, (size_t)N * 4, stream);
    hist_row<<<2048, 256, 0, stream>>>(edst, rcnt, E);
    scan_rows_a<<<NSC, 256, 0, stream>>>(rcnt, bsum);
    scan_rows_b<<<1, 64, 0, stream>>>(bsum, boff, row_ptr, E);
    scan_rows_c<<<NSC, 256, 0, stream>>>(rcnt, boff, row_ptr, cursor);

    // Fused: direct row scatter (1042 blocks) + gemm1 pre1 = bf16(X@W1) (782 blocks)
    scatter_gemm1<<<NPB + (N_NODES + 127) / 128, 256, 0, stream>>>(
        esrc, edst, adj, cursor, part, E, x, w1f_hi, w1f_lo, pre1, N);

    // Layer 1 SpMM: h = relu(A @ pre1) in fp32
    spmm_kernel<HIDDEN, true><<<(N + 3) / 4, 256, 0, stream>>>(pre1, part, row_ptr, h, N);

    // Layer 2: pre2 = bf16(h@W2) via MFMA ; out = A @ pre2 in fp32
    gemm_mfma<HIDDEN, OUT_DIM><<<(N + 127) / 128, 256, 0, stream>>>(h, w2f_hi, w2f_lo, pre2, N);
    spmm_kernel<OUT_DIM, false><<<(N + 3) / 4, 256, 0, stream>>>(pre2, part, row_ptr, out, N);
}